// Round 16
// baseline (30.907 us; speedup 1.0000x reference)
//
#include <hip/hip_runtime.h>

// Problem constants
constexpr int B_   = 2;
constexpr int CIN  = 64;
constexpr int N    = 128;
constexpr int T    = 24;
constexpr int HID  = 64;
constexpr int COUT = 64;
constexpr int NT   = N * T;             // 3072
constexpr int BT   = B_ * T;            // 48
constexpr int ATT_BLOCKS = B_ * N;      // 256
constexpr int XT_BLOCKS  = 32;
constexpr int WF_BLOCKS  = 16;
constexpr int PREP_BLOCKS = ATT_BLOCKS + XT_BLOCKS + WF_BLOCKS;  // 304
constexpr int ALL_BLOCKS  = BT * 8;     // 384

typedef __attribute__((ext_vector_type(8))) short short8;
typedef __attribute__((ext_vector_type(4))) float f32x4;

__device__ inline unsigned short f2bf(float f) {   // RNE float->bf16
    unsigned u = __float_as_uint(f);
    return (unsigned short)((u + 0x7FFFu + ((u >> 16) & 1u)) >> 16);
}

// ---------------------------------------------------------------------------
// prep body (R13-identical).
// ---------------------------------------------------------------------------
__device__ __forceinline__ void prep_body(
    int blk, int tid,
    const float* __restrict__ x,  const float* __restrict__ att,
    const float* __restrict__ W1, const float* __restrict__ b1,
    const float* __restrict__ W2, const float* __restrict__ b2,
    unsigned* __restrict__ xT32, unsigned* __restrict__ attT32,
    float* __restrict__ asum_g,
    unsigned short* __restrict__ WfvT, unsigned short* __restrict__ WfhT,
    float* __restrict__ bvb2, float* __restrict__ bh,
    unsigned* smem_u32)
{
    if (blk < ATT_BLOCKS) {
        float* ts   = (float*)smem_u32;          // [128][25]
        float* psum = ts + 3200;                 // [24][8]
        const int b = blk >> 7;
        const int i = blk & 127;

        const float* ab = att + ((size_t)b * N + i) * NT;
#pragma unroll
        for (int u = 0; u < 12; ++u) {
            const int idx = tid + 256 * u;
            const int j = idx / T, t = idx - j * T;
            ts[j * 25 + t] = ab[idx];
        }
        __syncthreads();
#pragma unroll
        for (int u = 0; u < 6; ++u) {
            const int e2 = tid + 256 * u;
            const int t = e2 >> 6, jp = e2 & 63, j = jp * 2;
            const unsigned pk = (unsigned)f2bf(ts[j * 25 + t])
                              | ((unsigned)f2bf(ts[(j + 1) * 25 + t]) << 16);
            attT32[((size_t)(b * T + t) * N + i) * 64 + jp] = pk;
        }
        if (tid < 192) {
            const int t = tid >> 3, p = tid & 7;
            float s = 0.f;
#pragma unroll
            for (int q = 0; q < 16; ++q) s += ts[(p * 16 + q) * 25 + t];
            psum[t * 8 + p] = s;
        }
        __syncthreads();
        if (tid < T) {
            float s = 0.f;
#pragma unroll
            for (int p = 0; p < 8; ++p) s += psum[tid * 8 + p];
            asum_g[(size_t)(b * T + tid) * N + i] = s;
        }
    } else if (blk < ATT_BLOCKS + XT_BLOCKS) {
        const int tb = blk - ATT_BLOCKS;
        const int b  = tb >> 4;
        const int n0 = (tb & 15) * 8;
#pragma unroll
        for (int u = 0; u < 12; ++u) {
            const int vidx = tid + 256 * u;
            const int cp = vidx / 48, w48 = vidx - cp * 48;
            const float4 v = *(const float4*)(x + (size_t)(b * CIN + cp) * NT
                                              + n0 * T + w48 * 4);
            smem_u32[cp * 97 + w48 * 2]     = (unsigned)f2bf(v.x) | ((unsigned)f2bf(v.y) << 16);
            smem_u32[cp * 97 + w48 * 2 + 1] = (unsigned)f2bf(v.z) | ((unsigned)f2bf(v.w) << 16);
        }
        __syncthreads();
#pragma unroll
        for (int v = 0; v < 24; ++v) {
            const int oidx = tid + 256 * v;
            const int t = oidx >> 8, rem = oidx & 255;
            const int n = rem >> 5, cp = rem & 31;
            const int r = n * T + t;
            const unsigned w0 = smem_u32[(2 * cp) * 97 + (r >> 1)];
            const unsigned w1 = smem_u32[(2 * cp + 1) * 97 + (r >> 1)];
            const unsigned v0 = (r & 1) ? (w0 >> 16) : (w0 & 0xFFFFu);
            const unsigned v1 = (r & 1) ? (w1 >> 16) : (w1 & 0xFFFFu);
            xT32[((size_t)(b * T + t) * N + n0 + n) * 32 + cp] = v0 | (v1 << 16);
        }
    } else {
        const int wf   = blk - (ATT_BLOCKS + XT_BLOCKS);
        const int half = wf >> 3;
        const int c0   = (wf & 7) * 8;
        float* sW1 = (float*)smem_u32;          // [64][65]
        float* sW2 = sW1 + 64 * 65;             // [64][65]
#pragma unroll
        for (int u = 0; u < 16; ++u) {
            const int i = tid + 256 * u;
            const int r = i >> 6, q = i & 63;
            sW1[r * 65 + q] = W1[i];
            sW2[r * 65 + q] = W2[half * 4096 + i];
        }
        __syncthreads();

        const int c = c0 + (tid & 7);
        const int r = tid >> 3;
        float a0 = 0.f, a1 = 0.f;
#pragma unroll
        for (int q = 0; q < 64; ++q) {
            const float w2 = sW2[q * 65 + c];
            a0 += sW1[r * 65 + q] * w2;
            a1 += sW1[(r + 32) * 65 + q] * w2;
        }
        unsigned short* dst = half ? WfhT : WfvT;
        dst[c * 64 + r]      = f2bf(a0);
        dst[c * 64 + r + 32] = f2bf(a1);

        if (tid < 8) {
            const int cb = c0 + tid;
            float s = 0.f;
#pragma unroll
            for (int q = 0; q < 64; ++q) s += b1[q] * sW2[q * 65 + cb];
            if (half) bh[cb] = s;
            else      bvb2[cb] = s + b2[cb];
        }
    }
}

__global__ __launch_bounds__(256) void k_prep(
    const float* __restrict__ x,  const float* __restrict__ att,
    const float* __restrict__ W1, const float* __restrict__ b1,
    const float* __restrict__ W2, const float* __restrict__ b2,
    unsigned* __restrict__ xT32, unsigned* __restrict__ attT32,
    float* __restrict__ asum_g,
    unsigned short* __restrict__ WfvT, unsigned short* __restrict__ WfhT,
    float* __restrict__ bvb2, float* __restrict__ bh)
{
    __shared__ __align__(16) unsigned smem_u32[8320];
    prep_body(blockIdx.x, threadIdx.x, x, att, W1, b1, W2, b2,
              xT32, attT32, asum_g, WfvT, WfhT, bvb2, bh, smem_u32);
}

// ---------------------------------------------------------------------------
// k_all: EXACT R13 copy (best-known config).
// ---------------------------------------------------------------------------
__global__ __launch_bounds__(256) void k_all(
    const unsigned short* __restrict__ xTb,
    const unsigned short* __restrict__ attTb,
    const unsigned short* __restrict__ WfvT,
    const unsigned short* __restrict__ WfhT,
    const float* __restrict__ bvb2,
    const float* __restrict__ bh,
    const float* __restrict__ asum_g,
    float* __restrict__ out)
{
    __shared__ __align__(8) unsigned short mhT[64][140];

    const int blk   = blockIdx.x;
    const int itile = blk & 7;
    const int bt    = blk >> 3;
    const int b     = bt / T;
    const int t     = bt - b * T;

    const int tid  = threadIdx.x;
    const int w    = tid >> 6;
    const int lane = tid & 63;
    const int c16  = lane & 15;
    const int q4   = lane >> 4;
    const int cc   = w * 16 + c16;

    const unsigned short* whr = WfhT + cc * 64;
    const short8 wh0 = *(const short8*)(whr + q4 * 8);
    const short8 wh1 = *(const short8*)(whr + 32 + q4 * 8);
    const unsigned short* wvr = WfvT + cc * 64;
    const short8 wv0 = *(const short8*)(wvr + q4 * 8);
    const short8 wv1 = *(const short8*)(wvr + 32 + q4 * 8);
    const float bhc = bh[cc];
    const float bvc = bvb2[cc];

    const unsigned short* xpanel = xTb + (size_t)bt * N * CIN;

    f32x4 accv = {0.f, 0.f, 0.f, 0.f};
#pragma unroll
    for (int nt8 = 0; nt8 < 8; ++nt8) {
        const unsigned short* xr = xpanel + (nt8 * 16 + c16) * CIN;
        const short8 a0 = *(const short8*)(xr + q4 * 8);
        const short8 a1 = *(const short8*)(xr + 32 + q4 * 8);
        f32x4 d = {0.f, 0.f, 0.f, 0.f};
        d = __builtin_amdgcn_mfma_f32_16x16x32_bf16(a0, wh0, d, 0, 0, 0);
        d = __builtin_amdgcn_mfma_f32_16x16x32_bf16(a1, wh1, d, 0, 0, 0);
        uint2 pk;
        pk.x = (unsigned)f2bf(d[0] + bhc) | ((unsigned)f2bf(d[1] + bhc) << 16);
        pk.y = (unsigned)f2bf(d[2] + bhc) | ((unsigned)f2bf(d[3] + bhc) << 16);
        *(uint2*)&mhT[cc][nt8 * 16 + q4 * 4] = pk;
        if (nt8 == itile) {
            accv = __builtin_amdgcn_mfma_f32_16x16x32_bf16(a0, wv0, accv, 0, 0, 0);
            accv = __builtin_amdgcn_mfma_f32_16x16x32_bf16(a1, wv1, accv, 0, 0, 0);
        }
    }
    __syncthreads();

    f32x4 acc = {0.f, 0.f, 0.f, 0.f};
    const unsigned short* arow = attTb + ((size_t)bt * N + itile * 16 + c16) * N;
#pragma unroll
    for (int ks = 0; ks < 4; ++ks) {
        const short8 a  = *(const short8*)(arow + ks * 32 + q4 * 8);
        const short8 bb = *(const short8*)(&mhT[cc][ks * 32 + q4 * 8]);
        acc = __builtin_amdgcn_mfma_f32_16x16x32_bf16(a, bb, acc, 0, 0, 0);
    }

    const int il0 = itile * 16 + q4 * 4;
    const f32x4 as4 = *(const f32x4*)(asum_g + (size_t)bt * N + il0);
    float* ob = out + (((size_t)b * COUT + cc) * N + il0) * T + t;
#pragma unroll
    for (int e = 0; e < 4; ++e) {
        ob[e * T] = acc[e] + as4[e] * (accv[e] + bvc);
    }
}

// ---------------------------------------------------------------------------
// R16 = R13 (real pipeline, 18.7us base) + serial slope probe on k_prep:
// 3 dummy k_prep replicas, each writing a DISTINCT scratch region (no
// same-address contention — the flaw that invalidated R12/R14 amp data).
// dur(R16) - 18.7 = 3 * (F + E_prep13).
// ---------------------------------------------------------------------------
extern "C" void kernel_launch(void* const* d_in, const int* in_sizes, int n_in,
                              void* d_out, int out_size, void* d_ws, size_t ws_size,
                              hipStream_t stream)
{
    const float* x   = (const float*)d_in[0];
    const float* att = (const float*)d_in[1];
    const float* W1  = (const float*)d_in[2];
    const float* b1  = (const float*)d_in[3];
    const float* W2  = (const float*)d_in[4];
    const float* b2  = (const float*)d_in[5];
    float* out = (float*)d_out;

    char* ws = (char*)d_ws;
    unsigned*       xT32   = (unsigned*)ws;                        //   786,432 B
    unsigned*       attT32 = (unsigned*)(ws + 786432);             // 1,572,864 B
    float*          asum_g = (float*)(ws + 2359296);               //    24,576 B
    unsigned short* WfvT   = (unsigned short*)(ws + 2383872);      //     8,192 B
    unsigned short* WfhT   = (unsigned short*)(ws + 2392064);      //     8,192 B
    float*          bvb2   = (float*)(ws + 2400256);               //       256 B
    float*          bh     = (float*)(ws + 2400512);               //       256 B

    // Real pipeline (R13-identical).
    k_prep<<<PREP_BLOCKS, 256, 0, stream>>>(x, att, W1, b1, W2, b2,
                                            xT32, attT32, asum_g,
                                            WfvT, WfhT, bvb2, bh);
    k_all<<<ALL_BLOCKS, 256, 0, stream>>>((const unsigned short*)xT32,
                                          (const unsigned short*)attT32,
                                          WfvT, WfhT, bvb2, bh, asum_g, out);

    // Serial slope probe: 3 dummy preps, DISTINCT 4 MiB scratch regions each.
    for (int d = 0; d < 3; ++d) {
        char* dmy = ws + 8388608 + (size_t)d * 4194304;
        unsigned*       xT32_d   = (unsigned*)dmy;
        unsigned*       attT32_d = (unsigned*)(dmy + 786432);
        float*          asum_d   = (float*)(dmy + 2359296);
        unsigned short* WfvT_d   = (unsigned short*)(dmy + 2383872);
        unsigned short* WfhT_d   = (unsigned short*)(dmy + 2392064);
        float*          bvb2_d   = (float*)(dmy + 2400256);
        float*          bh_d     = (float*)(dmy + 2400512);
        k_prep<<<PREP_BLOCKS, 256, 0, stream>>>(x, att, W1, b1, W2, b2,
                                                xT32_d, attT32_d, asum_d,
                                                WfvT_d, WfhT_d, bvb2_d, bh_d);
    }
}

// Round 17
// 19.520 us; speedup vs baseline: 1.5833x; 1.5833x over previous
//
#include <hip/hip_runtime.h>

// Problem constants
constexpr int B_   = 2;
constexpr int CIN  = 64;
constexpr int N    = 128;
constexpr int T    = 24;
constexpr int HID  = 64;
constexpr int COUT = 64;
constexpr int NT   = N * T;             // 3072
constexpr int BT   = B_ * T;            // 48
constexpr int ATT_BLOCKS = B_ * N;      // 256
constexpr int XT_BLOCKS  = 32;
constexpr int WF_BLOCKS  = 16;
constexpr int PREP_BLOCKS = ATT_BLOCKS + XT_BLOCKS + WF_BLOCKS;  // 304
constexpr int MID_BLOCKS  = BT * 4;     // 192 (bt, 32-row n-tile)
constexpr int FIN_BLOCKS  = BT * 8;     // 384 (bt, itile)

typedef __attribute__((ext_vector_type(8))) short short8;
typedef __attribute__((ext_vector_type(4))) float f32x4;

__device__ inline unsigned short f2bf(float f) {   // RNE float->bf16
    unsigned u = __float_as_uint(f);
    return (unsigned short)((u + 0x7FFFu + ((u >> 16) & 1u)) >> 16);
}

// ---------------------------------------------------------------------------
// k_prep: R13-byte-identical (E ~= 4.0us, slope-anchored R16).
// ---------------------------------------------------------------------------
__global__ __launch_bounds__(256) void k_prep(
    const float* __restrict__ x,
    const float* __restrict__ att,
    const float* __restrict__ W1,
    const float* __restrict__ b1,
    const float* __restrict__ W2,
    const float* __restrict__ b2,
    unsigned* __restrict__ xT32,
    unsigned* __restrict__ attT32,
    float* __restrict__ asum_g,
    unsigned short* __restrict__ WfvT,
    unsigned short* __restrict__ WfhT,
    float* __restrict__ bvb2,
    float* __restrict__ bh)
{
    __shared__ __align__(16) unsigned smem_u32[8320];
    const int tid = threadIdx.x;
    const int blk = blockIdx.x;

    if (blk < ATT_BLOCKS) {
        float* ts   = (float*)smem_u32;          // [128][25]
        float* psum = ts + 3200;                 // [24][8]
        const int b = blk >> 7;
        const int i = blk & 127;

        const float* ab = att + ((size_t)b * N + i) * NT;
#pragma unroll
        for (int u = 0; u < 12; ++u) {
            const int idx = tid + 256 * u;
            const int j = idx / T, t = idx - j * T;
            ts[j * 25 + t] = ab[idx];
        }
        __syncthreads();
#pragma unroll
        for (int u = 0; u < 6; ++u) {
            const int e2 = tid + 256 * u;
            const int t = e2 >> 6, jp = e2 & 63, j = jp * 2;
            const unsigned pk = (unsigned)f2bf(ts[j * 25 + t])
                              | ((unsigned)f2bf(ts[(j + 1) * 25 + t]) << 16);
            attT32[((size_t)(b * T + t) * N + i) * 64 + jp] = pk;
        }
        if (tid < 192) {
            const int t = tid >> 3, p = tid & 7;
            float s = 0.f;
#pragma unroll
            for (int q = 0; q < 16; ++q) s += ts[(p * 16 + q) * 25 + t];
            psum[t * 8 + p] = s;
        }
        __syncthreads();
        if (tid < T) {
            float s = 0.f;
#pragma unroll
            for (int p = 0; p < 8; ++p) s += psum[tid * 8 + p];
            asum_g[(size_t)(b * T + tid) * N + i] = s;
        }
    } else if (blk < ATT_BLOCKS + XT_BLOCKS) {
        const int tb = blk - ATT_BLOCKS;
        const int b  = tb >> 4;
        const int n0 = (tb & 15) * 8;
#pragma unroll
        for (int u = 0; u < 12; ++u) {
            const int vidx = tid + 256 * u;
            const int cp = vidx / 48, w48 = vidx - cp * 48;
            const float4 v = *(const float4*)(x + (size_t)(b * CIN + cp) * NT
                                              + n0 * T + w48 * 4);
            smem_u32[cp * 97 + w48 * 2]     = (unsigned)f2bf(v.x) | ((unsigned)f2bf(v.y) << 16);
            smem_u32[cp * 97 + w48 * 2 + 1] = (unsigned)f2bf(v.z) | ((unsigned)f2bf(v.w) << 16);
        }
        __syncthreads();
#pragma unroll
        for (int v = 0; v < 24; ++v) {
            const int oidx = tid + 256 * v;
            const int t = oidx >> 8, rem = oidx & 255;
            const int n = rem >> 5, cp = rem & 31;
            const int r = n * T + t;
            const unsigned w0 = smem_u32[(2 * cp) * 97 + (r >> 1)];
            const unsigned w1 = smem_u32[(2 * cp + 1) * 97 + (r >> 1)];
            const unsigned v0 = (r & 1) ? (w0 >> 16) : (w0 & 0xFFFFu);
            const unsigned v1 = (r & 1) ? (w1 >> 16) : (w1 & 0xFFFFu);
            xT32[((size_t)(b * T + t) * N + n0 + n) * 32 + cp] = v0 | (v1 << 16);
        }
    } else {
        const int wf   = blk - (ATT_BLOCKS + XT_BLOCKS);
        const int half = wf >> 3;
        const int c0   = (wf & 7) * 8;
        float* sW1 = (float*)smem_u32;          // [64][65]
        float* sW2 = sW1 + 64 * 65;             // [64][65]
#pragma unroll
        for (int u = 0; u < 16; ++u) {
            const int i = tid + 256 * u;
            const int r = i >> 6, q = i & 63;
            sW1[r * 65 + q] = W1[i];
            sW2[r * 65 + q] = W2[half * 4096 + i];
        }
        __syncthreads();

        const int c = c0 + (tid & 7);
        const int r = tid >> 3;
        float a0 = 0.f, a1 = 0.f;
#pragma unroll
        for (int q = 0; q < 64; ++q) {
            const float w2 = sW2[q * 65 + c];
            a0 += sW1[r * 65 + q] * w2;
            a1 += sW1[(r + 32) * 65 + q] * w2;
        }
        unsigned short* dst = half ? WfhT : WfvT;
        dst[c * 64 + r]      = f2bf(a0);
        dst[c * 64 + r + 32] = f2bf(a1);

        if (tid < 8) {
            const int cb = c0 + tid;
            float s = 0.f;
#pragma unroll
            for (int q = 0; q < 64; ++q) s += b1[q] * sW2[q * 65 + cb];
            if (half) bh[cb] = s;
            else      bvb2[cb] = s + b2[cb];
        }
    }
}

// ---------------------------------------------------------------------------
// k_mid: dedup'd MLP panels. Block = (bt, 32-row n-tile); wave = c-tile.
// Computes ONCE per bt (vs 8x redundant in R13's k_all):
//   mhT[bt][c][n] bf16 = (xT[bt] @ WfhT^T + bh)^T
//   mvT[bt][c][n] f32  = (xT[bt] @ WfvT^T + bvb2)^T
// Per wave: 2 row-tiles x (2+2) MFMAs. Stores in 32B (mhT) / 64B (mvT) runs.
// ---------------------------------------------------------------------------
__global__ __launch_bounds__(256) void k_mid(
    const unsigned short* __restrict__ xTb,
    const unsigned short* __restrict__ WfvT,
    const unsigned short* __restrict__ WfhT,
    const float* __restrict__ bvb2,
    const float* __restrict__ bh,
    unsigned short* __restrict__ mhT,
    float* __restrict__ mvT)
{
    const int blk  = blockIdx.x;
    const int nt32 = blk & 3;            // 32-row n-tile
    const int bt   = blk >> 2;
    const int n0   = nt32 * 32;

    const int tid  = threadIdx.x;
    const int w    = tid >> 6;           // c-tile
    const int lane = tid & 63;
    const int c16  = lane & 15;
    const int q4   = lane >> 4;
    const int cc   = w * 16 + c16;

    const unsigned short* whr = WfhT + cc * 64;
    const short8 wh0 = *(const short8*)(whr + q4 * 8);
    const short8 wh1 = *(const short8*)(whr + 32 + q4 * 8);
    const unsigned short* wvr = WfvT + cc * 64;
    const short8 wv0 = *(const short8*)(wvr + q4 * 8);
    const short8 wv1 = *(const short8*)(wvr + 32 + q4 * 8);
    const float bhc = bh[cc];
    const float bvc = bvb2[cc];

    const unsigned short* xpanel = xTb + (size_t)bt * N * CIN;

#pragma unroll
    for (int rt = 0; rt < 2; ++rt) {
        const int nbase = n0 + rt * 16;
        const unsigned short* xr = xpanel + (nbase + c16) * CIN;
        const short8 a0 = *(const short8*)(xr + q4 * 8);
        const short8 a1 = *(const short8*)(xr + 32 + q4 * 8);

        f32x4 dh = {0.f, 0.f, 0.f, 0.f};
        dh = __builtin_amdgcn_mfma_f32_16x16x32_bf16(a0, wh0, dh, 0, 0, 0);
        dh = __builtin_amdgcn_mfma_f32_16x16x32_bf16(a1, wh1, dh, 0, 0, 0);
        f32x4 dv = {0.f, 0.f, 0.f, 0.f};
        dv = __builtin_amdgcn_mfma_f32_16x16x32_bf16(a0, wv0, dv, 0, 0, 0);
        dv = __builtin_amdgcn_mfma_f32_16x16x32_bf16(a1, wv1, dv, 0, 0, 0);

        // d[e] = panel[row n = nbase + q4*4 + e][col cc]
        const int nn = nbase + q4 * 4;
        uint2 pk;
        pk.x = (unsigned)f2bf(dh[0] + bhc) | ((unsigned)f2bf(dh[1] + bhc) << 16);
        pk.y = (unsigned)f2bf(dh[2] + bhc) | ((unsigned)f2bf(dh[3] + bhc) << 16);
        *(uint2*)&mhT[((size_t)bt * COUT + cc) * N + nn] = pk;

        f32x4 v;
        v[0] = dv[0] + bvc; v[1] = dv[1] + bvc;
        v[2] = dv[2] + bvc; v[3] = dv[3] + bvc;
        *(f32x4*)&mvT[((size_t)bt * COUT + cc) * N + nn] = v;
    }
}

// ---------------------------------------------------------------------------
// k_fin: R6's k_att VERBATIM (E = 4.9us, slope-anchored R8).
//   D(16x16) = attT_tile(16x128) @ mhT^T(128x16), 4 MFMAs; epilogue adds
//   asum_i * mvT[bt][c][i]; out[b][c][i][t] scatter.
// ---------------------------------------------------------------------------
__global__ __launch_bounds__(256) void k_fin(
    const unsigned short* __restrict__ attTb,
    const unsigned short* __restrict__ mhT,
    const float* __restrict__ mvT,
    const float* __restrict__ asum_g,
    float* __restrict__ out)
{
    const int blk   = blockIdx.x;
    const int itile = blk & 7;
    const int bt    = blk >> 3;
    const int b     = bt / T;
    const int t     = bt - b * T;

    const int tid  = threadIdx.x;
    const int w    = tid >> 6;
    const int lane = tid & 63;
    const int c16  = lane & 15;
    const int q4   = lane >> 4;
    const int n0   = w * 16;

    const unsigned short* arow = attTb + ((size_t)bt * N + itile * 16 + c16) * N;
    const unsigned short* brow = mhT   + ((size_t)bt * COUT + n0 + c16) * N;

    f32x4 acc = {0.f, 0.f, 0.f, 0.f};
#pragma unroll
    for (int ks = 0; ks < 4; ++ks) {
        const short8 a  = *(const short8*)(arow + ks * 32 + q4 * 8);
        const short8 bb = *(const short8*)(brow + ks * 32 + q4 * 8);
        acc = __builtin_amdgcn_mfma_f32_16x16x32_bf16(a, bb, acc, 0, 0, 0);
    }

    const int il0 = itile * 16 + q4 * 4;
    const int cc  = n0 + c16;

    const f32x4 mb  = *(const f32x4*)(mvT + ((size_t)bt * COUT + cc) * N + il0);
    const f32x4 as4 = *(const f32x4*)(asum_g + (size_t)bt * N + il0);

    float* ob = out + (((size_t)b * COUT + cc) * N + il0) * T + t;
#pragma unroll
    for (int e = 0; e < 4; ++e) {
        ob[e * T] = acc[e] + as4[e] * mb[e];
    }
}

// ---------------------------------------------------------------------------
extern "C" void kernel_launch(void* const* d_in, const int* in_sizes, int n_in,
                              void* d_out, int out_size, void* d_ws, size_t ws_size,
                              hipStream_t stream)
{
    const float* x   = (const float*)d_in[0];
    const float* att = (const float*)d_in[1];
    const float* W1  = (const float*)d_in[2];
    const float* b1  = (const float*)d_in[3];
    const float* W2  = (const float*)d_in[4];
    const float* b2  = (const float*)d_in[5];
    float* out = (float*)d_out;

    char* ws = (char*)d_ws;
    unsigned*       xT32   = (unsigned*)ws;                        //   786,432 B
    unsigned*       attT32 = (unsigned*)(ws + 786432);             // 1,572,864 B
    float*          asum_g = (float*)(ws + 2359296);               //    24,576 B
    unsigned short* WfvT   = (unsigned short*)(ws + 2383872);      //     8,192 B
    unsigned short* WfhT   = (unsigned short*)(ws + 2392064);      //     8,192 B
    float*          bvb2   = (float*)(ws + 2400256);               //       256 B
    float*          bh     = (float*)(ws + 2400512);               //       256 B
    unsigned short* mhT    = (unsigned short*)(ws + 2400768);      //   786,432 B
    float*          mvT    = (float*)(ws + 3187200);               // 1,572,864 B

    k_prep<<<PREP_BLOCKS, 256, 0, stream>>>(x, att, W1, b1, W2, b2,
                                            xT32, attT32, asum_g,
                                            WfvT, WfhT, bvb2, bh);
    k_mid<<<MID_BLOCKS, 256, 0, stream>>>((const unsigned short*)xT32,
                                          WfvT, WfhT, bvb2, bh, mhT, mvT);
    k_fin<<<FIN_BLOCKS, 256, 0, stream>>>((const unsigned short*)attT32,
                                          mhT, mvT, asum_g, out);
}

// Round 18
// 18.383 us; speedup vs baseline: 1.6813x; 1.0619x over previous
//
#include <hip/hip_runtime.h>

// Problem constants
constexpr int B_   = 2;
constexpr int CIN  = 64;
constexpr int N    = 128;
constexpr int T    = 24;
constexpr int HID  = 64;
constexpr int COUT = 64;
constexpr int NT   = N * T;             // 3072
constexpr int BT   = B_ * T;            // 48
constexpr int ATT_BLOCKS = B_ * N;      // 256
constexpr int XT_BLOCKS  = 32;
constexpr int WF_BLOCKS  = 16;
constexpr int PREP_BLOCKS = ATT_BLOCKS + XT_BLOCKS + WF_BLOCKS;  // 304
constexpr int MAIN_BLOCKS = BT * 2;     // 96 = (bt, c-half)

typedef __attribute__((ext_vector_type(8))) short short8;
typedef __attribute__((ext_vector_type(4))) float f32x4;

__device__ inline unsigned short f2bf(float f) {   // RNE float->bf16
    unsigned u = __float_as_uint(f);
    return (unsigned short)((u + 0x7FFFu + ((u >> 16) & 1u)) >> 16);
}

// ---------------------------------------------------------------------------
// k_prep: R13-byte-identical (E ~= 4.0us, slope-anchored R16).
// ---------------------------------------------------------------------------
__global__ __launch_bounds__(256) void k_prep(
    const float* __restrict__ x,
    const float* __restrict__ att,
    const float* __restrict__ W1,
    const float* __restrict__ b1,
    const float* __restrict__ W2,
    const float* __restrict__ b2,
    unsigned* __restrict__ xT32,
    unsigned* __restrict__ attT32,
    float* __restrict__ asum_g,
    unsigned short* __restrict__ WfvT,
    unsigned short* __restrict__ WfhT,
    float* __restrict__ bvb2,
    float* __restrict__ bh)
{
    __shared__ __align__(16) unsigned smem_u32[8320];
    const int tid = threadIdx.x;
    const int blk = blockIdx.x;

    if (blk < ATT_BLOCKS) {
        float* ts   = (float*)smem_u32;          // [128][25]
        float* psum = ts + 3200;                 // [24][8]
        const int b = blk >> 7;
        const int i = blk & 127;

        const float* ab = att + ((size_t)b * N + i) * NT;
#pragma unroll
        for (int u = 0; u < 12; ++u) {
            const int idx = tid + 256 * u;
            const int j = idx / T, t = idx - j * T;
            ts[j * 25 + t] = ab[idx];
        }
        __syncthreads();
#pragma unroll
        for (int u = 0; u < 6; ++u) {
            const int e2 = tid + 256 * u;
            const int t = e2 >> 6, jp = e2 & 63, j = jp * 2;
            const unsigned pk = (unsigned)f2bf(ts[j * 25 + t])
                              | ((unsigned)f2bf(ts[(j + 1) * 25 + t]) << 16);
            attT32[((size_t)(b * T + t) * N + i) * 64 + jp] = pk;
        }
        if (tid < 192) {
            const int t = tid >> 3, p = tid & 7;
            float s = 0.f;
#pragma unroll
            for (int q = 0; q < 16; ++q) s += ts[(p * 16 + q) * 25 + t];
            psum[t * 8 + p] = s;
        }
        __syncthreads();
        if (tid < T) {
            float s = 0.f;
#pragma unroll
            for (int p = 0; p < 8; ++p) s += psum[tid * 8 + p];
            asum_g[(size_t)(b * T + tid) * N + i] = s;
        }
    } else if (blk < ATT_BLOCKS + XT_BLOCKS) {
        const int tb = blk - ATT_BLOCKS;
        const int b  = tb >> 4;
        const int n0 = (tb & 15) * 8;
#pragma unroll
        for (int u = 0; u < 12; ++u) {
            const int vidx = tid + 256 * u;
            const int cp = vidx / 48, w48 = vidx - cp * 48;
            const float4 v = *(const float4*)(x + (size_t)(b * CIN + cp) * NT
                                              + n0 * T + w48 * 4);
            smem_u32[cp * 97 + w48 * 2]     = (unsigned)f2bf(v.x) | ((unsigned)f2bf(v.y) << 16);
            smem_u32[cp * 97 + w48 * 2 + 1] = (unsigned)f2bf(v.z) | ((unsigned)f2bf(v.w) << 16);
        }
        __syncthreads();
#pragma unroll
        for (int v = 0; v < 24; ++v) {
            const int oidx = tid + 256 * v;
            const int t = oidx >> 8, rem = oidx & 255;
            const int n = rem >> 5, cp = rem & 31;
            const int r = n * T + t;
            const unsigned w0 = smem_u32[(2 * cp) * 97 + (r >> 1)];
            const unsigned w1 = smem_u32[(2 * cp + 1) * 97 + (r >> 1)];
            const unsigned v0 = (r & 1) ? (w0 >> 16) : (w0 & 0xFFFFu);
            const unsigned v1 = (r & 1) ? (w1 >> 16) : (w1 & 0xFFFFu);
            xT32[((size_t)(b * T + t) * N + n0 + n) * 32 + cp] = v0 | (v1 << 16);
        }
    } else {
        const int wf   = blk - (ATT_BLOCKS + XT_BLOCKS);
        const int half = wf >> 3;
        const int c0   = (wf & 7) * 8;
        float* sW1 = (float*)smem_u32;          // [64][65]
        float* sW2 = sW1 + 64 * 65;             // [64][65]
#pragma unroll
        for (int u = 0; u < 16; ++u) {
            const int i = tid + 256 * u;
            const int r = i >> 6, q = i & 63;
            sW1[r * 65 + q] = W1[i];
            sW2[r * 65 + q] = W2[half * 4096 + i];
        }
        __syncthreads();

        const int c = c0 + (tid & 7);
        const int r = tid >> 3;
        float a0 = 0.f, a1 = 0.f;
#pragma unroll
        for (int q = 0; q < 64; ++q) {
            const float w2 = sW2[q * 65 + c];
            a0 += sW1[r * 65 + q] * w2;
            a1 += sW1[(r + 32) * 65 + q] * w2;
        }
        unsigned short* dst = half ? WfhT : WfvT;
        dst[c * 64 + r]      = f2bf(a0);
        dst[c * 64 + r + 32] = f2bf(a1);

        if (tid < 8) {
            const int cb = c0 + tid;
            float s = 0.f;
#pragma unroll
            for (int q = 0; q < 64; ++q) s += b1[q] * sW2[q * 65 + cb];
            if (half) bh[cb] = s;
            else      bvb2[cb] = s + b2[cb];
        }
    }
}

// ---------------------------------------------------------------------------
// k_main: fused mid+fin. Block = (bt, c-half); 512 threads = 8 waves.
//  Hoist: att A-frags + asum loaded FIRST (one global-latency epoch).
//  Phase 1 (wave w = n-tile w): mh/mv half-panels (128n x 32c) computed ONCE,
//    A-frags (x rows) reused across both c-tiles; 8 MFMAs/wave; panels -> LDS.
//  Phase 2 (wave w = i-tile w): einsum acc(16i x 16c) for both c-tiles,
//    A = hoisted att frags, B = LDS mh; 8 MFMAs/wave.
//  Epilogue: out[b][cc][i][t] = acc + asum_i * mv_lds[cc][i].
//  All LDS patterns 2-way bank-aliased (free). No global round-trip for mh/mv.
// ---------------------------------------------------------------------------
__global__ __launch_bounds__(512) void k_main(
    const unsigned short* __restrict__ xTb,
    const unsigned short* __restrict__ attTb,
    const unsigned short* __restrict__ WfvT,
    const unsigned short* __restrict__ WfhT,
    const float* __restrict__ bvb2,
    const float* __restrict__ bh,
    const float* __restrict__ asum_g,
    float* __restrict__ out)
{
    __shared__ __align__(8) unsigned short mh_lds[32][136];  //  8.5 KB
    __shared__ __align__(16) float         mv_lds[32][132];  // 16.5 KB

    const int blk   = blockIdx.x;
    const int chalf = blk & 1;
    const int bt    = blk >> 1;
    const int b     = bt / T;
    const int t     = bt - b * T;
    const int c0    = chalf * 32;

    const int tid  = threadIdx.x;
    const int w    = tid >> 6;            // 0..7 : n-tile (ph1) / i-tile (ph2)
    const int lane = tid & 63;
    const int c16  = lane & 15;
    const int q4   = lane >> 4;

    // ---- Hoisted global loads: att frags + asum (phase-2 inputs) ----
    const unsigned short* arow = attTb + ((size_t)bt * N + w * 16 + c16) * N;
    const short8 at0 = *(const short8*)(arow + 0 * 32 + q4 * 8);
    const short8 at1 = *(const short8*)(arow + 1 * 32 + q4 * 8);
    const short8 at2 = *(const short8*)(arow + 2 * 32 + q4 * 8);
    const short8 at3 = *(const short8*)(arow + 3 * 32 + q4 * 8);
    const int il0 = w * 16 + q4 * 4;
    const f32x4 as4 = *(const f32x4*)(asum_g + (size_t)bt * N + il0);

    // ---- Weights for this wave's two c-tiles (cc0 = c0+c16, cc1 = +16) ----
    const int cc0 = c0 + c16;
    const int cc1 = c0 + 16 + c16;
    const short8 wh00 = *(const short8*)(WfhT + cc0 * 64 + q4 * 8);
    const short8 wh01 = *(const short8*)(WfhT + cc0 * 64 + 32 + q4 * 8);
    const short8 wh10 = *(const short8*)(WfhT + cc1 * 64 + q4 * 8);
    const short8 wh11 = *(const short8*)(WfhT + cc1 * 64 + 32 + q4 * 8);
    const short8 wv00 = *(const short8*)(WfvT + cc0 * 64 + q4 * 8);
    const short8 wv01 = *(const short8*)(WfvT + cc0 * 64 + 32 + q4 * 8);
    const short8 wv10 = *(const short8*)(WfvT + cc1 * 64 + q4 * 8);
    const short8 wv11 = *(const short8*)(WfvT + cc1 * 64 + 32 + q4 * 8);
    const float bh0 = bh[cc0],   bh1 = bh[cc1];
    const float bv0 = bvb2[cc0], bv1 = bvb2[cc1];

    // ---- Phase 1: mh/mv half-panels for n-tile w (rows w*16..w*16+15) ----
    const unsigned short* xr = xTb + ((size_t)bt * N + w * 16 + c16) * CIN;
    const short8 a0 = *(const short8*)(xr + q4 * 8);
    const short8 a1 = *(const short8*)(xr + 32 + q4 * 8);

    f32x4 dh0 = {0.f,0.f,0.f,0.f}, dh1 = {0.f,0.f,0.f,0.f};
    f32x4 dv0 = {0.f,0.f,0.f,0.f}, dv1 = {0.f,0.f,0.f,0.f};
    dh0 = __builtin_amdgcn_mfma_f32_16x16x32_bf16(a0, wh00, dh0, 0, 0, 0);
    dh0 = __builtin_amdgcn_mfma_f32_16x16x32_bf16(a1, wh01, dh0, 0, 0, 0);
    dh1 = __builtin_amdgcn_mfma_f32_16x16x32_bf16(a0, wh10, dh1, 0, 0, 0);
    dh1 = __builtin_amdgcn_mfma_f32_16x16x32_bf16(a1, wh11, dh1, 0, 0, 0);
    dv0 = __builtin_amdgcn_mfma_f32_16x16x32_bf16(a0, wv00, dv0, 0, 0, 0);
    dv0 = __builtin_amdgcn_mfma_f32_16x16x32_bf16(a1, wv01, dv0, 0, 0, 0);
    dv1 = __builtin_amdgcn_mfma_f32_16x16x32_bf16(a0, wv10, dv1, 0, 0, 0);
    dv1 = __builtin_amdgcn_mfma_f32_16x16x32_bf16(a1, wv11, dv1, 0, 0, 0);

    // D mapping: d[e] = tile[row n = w*16 + q4*4 + e][col c16(+16)]
    {
        const int nn = w * 16 + q4 * 4;
        uint2 p0;
        p0.x = (unsigned)f2bf(dh0[0] + bh0) | ((unsigned)f2bf(dh0[1] + bh0) << 16);
        p0.y = (unsigned)f2bf(dh0[2] + bh0) | ((unsigned)f2bf(dh0[3] + bh0) << 16);
        *(uint2*)&mh_lds[c16][nn] = p0;
        uint2 p1;
        p1.x = (unsigned)f2bf(dh1[0] + bh1) | ((unsigned)f2bf(dh1[1] + bh1) << 16);
        p1.y = (unsigned)f2bf(dh1[2] + bh1) | ((unsigned)f2bf(dh1[3] + bh1) << 16);
        *(uint2*)&mh_lds[16 + c16][nn] = p1;
#pragma unroll
        for (int e = 0; e < 4; ++e) {
            mv_lds[c16][nn + e]      = dv0[e] + bv0;
            mv_lds[16 + c16][nn + e] = dv1[e] + bv1;
        }
    }
    __syncthreads();

    // ---- Phase 2: einsum for i-tile w, both c-tiles ----
    f32x4 acc0 = {0.f,0.f,0.f,0.f}, acc1 = {0.f,0.f,0.f,0.f};
#pragma unroll
    for (int ks = 0; ks < 4; ++ks) {
        const short8 a = (ks == 0) ? at0 : (ks == 1) ? at1 : (ks == 2) ? at2 : at3;
        const short8 b0 = *(const short8*)(&mh_lds[c16][ks * 32 + q4 * 8]);
        const short8 b1v = *(const short8*)(&mh_lds[16 + c16][ks * 32 + q4 * 8]);
        acc0 = __builtin_amdgcn_mfma_f32_16x16x32_bf16(a, b0,  acc0, 0, 0, 0);
        acc1 = __builtin_amdgcn_mfma_f32_16x16x32_bf16(a, b1v, acc1, 0, 0, 0);
    }

    // ---- Epilogue: out[b][cc][i][t] = acc + asum_i * mv[cc][i] ----
    float* ob0 = out + (((size_t)b * COUT + cc0) * N + il0) * T + t;
    float* ob1 = out + (((size_t)b * COUT + cc1) * N + il0) * T + t;
#pragma unroll
    for (int e = 0; e < 4; ++e) {
        ob0[e * T] = acc0[e] + as4[e] * mv_lds[c16][il0 + e];
        ob1[e * T] = acc1[e] + as4[e] * mv_lds[16 + c16][il0 + e];
    }
}

// ---------------------------------------------------------------------------
extern "C" void kernel_launch(void* const* d_in, const int* in_sizes, int n_in,
                              void* d_out, int out_size, void* d_ws, size_t ws_size,
                              hipStream_t stream)
{
    const float* x   = (const float*)d_in[0];
    const float* att = (const float*)d_in[1];
    const float* W1  = (const float*)d_in[2];
    const float* b1  = (const float*)d_in[3];
    const float* W2  = (const float*)d_in[4];
    const float* b2  = (const float*)d_in[5];
    float* out = (float*)d_out;

    char* ws = (char*)d_ws;
    unsigned*       xT32   = (unsigned*)ws;                        //   786,432 B
    unsigned*       attT32 = (unsigned*)(ws + 786432);             // 1,572,864 B
    float*          asum_g = (float*)(ws + 2359296);               //    24,576 B
    unsigned short* WfvT   = (unsigned short*)(ws + 2383872);      //     8,192 B
    unsigned short* WfhT   = (unsigned short*)(ws + 2392064);      //     8,192 B
    float*          bvb2   = (float*)(ws + 2400256);               //       256 B
    float*          bh     = (float*)(ws + 2400512);               //       256 B

    k_prep<<<PREP_BLOCKS, 256, 0, stream>>>(x, att, W1, b1, W2, b2,
                                            xT32, attT32, asum_g,
                                            WfvT, WfhT, bvb2, bh);
    k_main<<<MAIN_BLOCKS, 512, 0, stream>>>((const unsigned short*)xT32,
                                            (const unsigned short*)attT32,
                                            WfvT, WfhT, bvb2, bh, asum_g, out);
}

// Round 19
// 18.365 us; speedup vs baseline: 1.6830x; 1.0010x over previous
//
#include <hip/hip_runtime.h>

// Problem constants
constexpr int B_   = 2;
constexpr int CIN  = 64;
constexpr int N    = 128;
constexpr int T    = 24;
constexpr int HID  = 64;
constexpr int COUT = 64;
constexpr int NT   = N * T;             // 3072
constexpr int BT   = B_ * T;            // 48
constexpr int ATT_BLOCKS = B_ * N;      // 256
constexpr int XT_BLOCKS  = 32;
constexpr int WF_BLOCKS  = 16;
constexpr int PREP_BLOCKS = ATT_BLOCKS + XT_BLOCKS + WF_BLOCKS;  // 304
constexpr int MAIN_BLOCKS = BT * 2;     // 96 = (bt, i-half)

typedef __attribute__((ext_vector_type(8))) short short8;
typedef __attribute__((ext_vector_type(4))) float f32x4;

__device__ inline unsigned short f2bf(float f) {   // RNE float->bf16
    unsigned u = __float_as_uint(f);
    return (unsigned short)((u + 0x7FFFu + ((u >> 16) & 1u)) >> 16);
}

// ---------------------------------------------------------------------------
// k_prep: R13-byte-identical (E ~= 4.0us, slope-anchored R16).
// ---------------------------------------------------------------------------
__global__ __launch_bounds__(256) void k_prep(
    const float* __restrict__ x,
    const float* __restrict__ att,
    const float* __restrict__ W1,
    const float* __restrict__ b1,
    const float* __restrict__ W2,
    const float* __restrict__ b2,
    unsigned* __restrict__ xT32,
    unsigned* __restrict__ attT32,
    float* __restrict__ asum_g,
    unsigned short* __restrict__ WfvT,
    unsigned short* __restrict__ WfhT,
    float* __restrict__ bvb2,
    float* __restrict__ bh)
{
    __shared__ __align__(16) unsigned smem_u32[8320];
    const int tid = threadIdx.x;
    const int blk = blockIdx.x;

    if (blk < ATT_BLOCKS) {
        float* ts   = (float*)smem_u32;          // [128][25]
        float* psum = ts + 3200;                 // [24][8]
        const int b = blk >> 7;
        const int i = blk & 127;

        const float* ab = att + ((size_t)b * N + i) * NT;
#pragma unroll
        for (int u = 0; u < 12; ++u) {
            const int idx = tid + 256 * u;
            const int j = idx / T, t = idx - j * T;
            ts[j * 25 + t] = ab[idx];
        }
        __syncthreads();
#pragma unroll
        for (int u = 0; u < 6; ++u) {
            const int e2 = tid + 256 * u;
            const int t = e2 >> 6, jp = e2 & 63, j = jp * 2;
            const unsigned pk = (unsigned)f2bf(ts[j * 25 + t])
                              | ((unsigned)f2bf(ts[(j + 1) * 25 + t]) << 16);
            attT32[((size_t)(b * T + t) * N + i) * 64 + jp] = pk;
        }
        if (tid < 192) {
            const int t = tid >> 3, p = tid & 7;
            float s = 0.f;
#pragma unroll
            for (int q = 0; q < 16; ++q) s += ts[(p * 16 + q) * 25 + t];
            psum[t * 8 + p] = s;
        }
        __syncthreads();
        if (tid < T) {
            float s = 0.f;
#pragma unroll
            for (int p = 0; p < 8; ++p) s += psum[tid * 8 + p];
            asum_g[(size_t)(b * T + tid) * N + i] = s;
        }
    } else if (blk < ATT_BLOCKS + XT_BLOCKS) {
        const int tb = blk - ATT_BLOCKS;
        const int b  = tb >> 4;
        const int n0 = (tb & 15) * 8;
#pragma unroll
        for (int u = 0; u < 12; ++u) {
            const int vidx = tid + 256 * u;
            const int cp = vidx / 48, w48 = vidx - cp * 48;
            const float4 v = *(const float4*)(x + (size_t)(b * CIN + cp) * NT
                                              + n0 * T + w48 * 4);
            smem_u32[cp * 97 + w48 * 2]     = (unsigned)f2bf(v.x) | ((unsigned)f2bf(v.y) << 16);
            smem_u32[cp * 97 + w48 * 2 + 1] = (unsigned)f2bf(v.z) | ((unsigned)f2bf(v.w) << 16);
        }
        __syncthreads();
#pragma unroll
        for (int v = 0; v < 24; ++v) {
            const int oidx = tid + 256 * v;
            const int t = oidx >> 8, rem = oidx & 255;
            const int n = rem >> 5, cp = rem & 31;
            const int r = n * T + t;
            const unsigned w0 = smem_u32[(2 * cp) * 97 + (r >> 1)];
            const unsigned w1 = smem_u32[(2 * cp + 1) * 97 + (r >> 1)];
            const unsigned v0 = (r & 1) ? (w0 >> 16) : (w0 & 0xFFFFu);
            const unsigned v1 = (r & 1) ? (w1 >> 16) : (w1 & 0xFFFFu);
            xT32[((size_t)(b * T + t) * N + n0 + n) * 32 + cp] = v0 | (v1 << 16);
        }
    } else {
        const int wf   = blk - (ATT_BLOCKS + XT_BLOCKS);
        const int half = wf >> 3;
        const int c0   = (wf & 7) * 8;
        float* sW1 = (float*)smem_u32;          // [64][65]
        float* sW2 = sW1 + 64 * 65;             // [64][65]
#pragma unroll
        for (int u = 0; u < 16; ++u) {
            const int i = tid + 256 * u;
            const int r = i >> 6, q = i & 63;
            sW1[r * 65 + q] = W1[i];
            sW2[r * 65 + q] = W2[half * 4096 + i];
        }
        __syncthreads();

        const int c = c0 + (tid & 7);
        const int r = tid >> 3;
        float a0 = 0.f, a1 = 0.f;
#pragma unroll
        for (int q = 0; q < 64; ++q) {
            const float w2 = sW2[q * 65 + c];
            a0 += sW1[r * 65 + q] * w2;
            a1 += sW1[(r + 32) * 65 + q] * w2;
        }
        unsigned short* dst = half ? WfhT : WfvT;
        dst[c * 64 + r]      = f2bf(a0);
        dst[c * 64 + r + 32] = f2bf(a1);

        if (tid < 8) {
            const int cb = c0 + tid;
            float s = 0.f;
#pragma unroll
            for (int q = 0; q < 64; ++q) s += b1[q] * sW2[q * 65 + cb];
            if (half) bh[cb] = s;
            else      bvb2[cb] = s + b2[cb];
        }
    }
}

// ---------------------------------------------------------------------------
// k_main v2: ALL cold ws reads are linear uint4 streams into LDS.
//  Block = (bt, ihalf); 512 threads = 8 waves.
//  Stage 0: xT[bt] (16 KB) + attT[bt][ihalf-slab] (16 KB), coalesced uint4.
//  Phase 1: wave w = n-tile w: mh[n-tile w][all 64 c] (8 MFMAs) -> mh_lds;
//           mv for its phase-2 (i-tile, c-pair) (4 MFMAs) -> regs.
//  Phase 2: wave w = i-tile (w&3) of this half, c-pair (w>>2):
//           einsum acc = att_tile @ mh (8 MFMAs, A+B from LDS).
//  Epilogue: out[b][cc][i][t] = acc + asum_i * (mv + bvb2).
// ---------------------------------------------------------------------------
__global__ __launch_bounds__(512) void k_main(
    const unsigned* __restrict__ xT32,
    const unsigned* __restrict__ attT32,
    const unsigned short* __restrict__ WfvT,
    const unsigned short* __restrict__ WfhT,
    const float* __restrict__ bvb2,
    const float* __restrict__ bh,
    const float* __restrict__ asum_g,
    float* __restrict__ out)
{
    __shared__ __align__(16) unsigned x_lds[128][36];        // 18,432 B
    __shared__ __align__(16) unsigned att_lds[64][68];       // 17,408 B
    __shared__ __align__(16) unsigned short mh_lds[64][136]; // 17,408 B

    const int blk   = blockIdx.x;
    const int ihalf = blk & 1;
    const int bt    = blk >> 1;
    const int b     = bt / T;
    const int t     = bt - b * T;

    const int tid  = threadIdx.x;
    const int w    = tid >> 6;
    const int lane = tid & 63;
    const int c16  = lane & 15;
    const int q4   = lane >> 4;

    // ---- Stage 0: linear streams (the ONLY cold ws reads) ----
    {
        const uint4* src = (const uint4*)(xT32 + (size_t)bt * 4096);
#pragma unroll
        for (int u = 0; u < 2; ++u) {
            const int vi = tid + 512 * u;        // uint4 idx < 1024
            const uint4 v = src[vi];
            *(uint4*)&x_lds[vi >> 3][(vi & 7) * 4] = v;
        }
    }
    {
        const uint4* src = (const uint4*)(attT32 + ((size_t)bt * 128 + ihalf * 64) * 64);
#pragma unroll
        for (int u = 0; u < 2; ++u) {
            const int vi = tid + 512 * u;        // uint4 idx < 1024
            const uint4 v = src[vi];
            *(uint4*)&att_lds[vi >> 4][(vi & 15) * 4] = v;
        }
    }

    // ---- Small global loads (weights/biases/asum — tiny, broadcast) ----
    const int ct0 = (w >> 2) * 2;                // this wave's c-pair base
    short8 wh0[4], wh1[4];
#pragma unroll
    for (int ct = 0; ct < 4; ++ct) {
        wh0[ct] = *(const short8*)(WfhT + (ct * 16 + c16) * 64 + q4 * 8);
        wh1[ct] = *(const short8*)(WfhT + (ct * 16 + c16) * 64 + 32 + q4 * 8);
    }
    short8 wv0[2], wv1[2];
#pragma unroll
    for (int p = 0; p < 2; ++p) {
        wv0[p] = *(const short8*)(WfvT + ((ct0 + p) * 16 + c16) * 64 + q4 * 8);
        wv1[p] = *(const short8*)(WfvT + ((ct0 + p) * 16 + c16) * 64 + 32 + q4 * 8);
    }
    float bhc[4];
#pragma unroll
    for (int ct = 0; ct < 4; ++ct) bhc[ct] = bh[ct * 16 + c16];
    float bvc[2];
#pragma unroll
    for (int p = 0; p < 2; ++p) bvc[p] = bvb2[(ct0 + p) * 16 + c16];

    const int il_base = ihalf * 64 + (w & 3) * 16;   // phase-2 i-tile base
    const f32x4 as4 = *(const f32x4*)(asum_g + (size_t)bt * N + il_base + q4 * 4);

    __syncthreads();

    // ---- Phase 1: mh (n-tile w, all c) -> LDS ; mv (own phase-2 tile) -> regs
    const short8 a0 = *(const short8*)&x_lds[w * 16 + c16][q4 * 4];
    const short8 a1 = *(const short8*)&x_lds[w * 16 + c16][16 + q4 * 4];
    const int nt_mv = ihalf * 4 + (w & 3);           // = il_base/16
    const short8 m0 = *(const short8*)&x_lds[nt_mv * 16 + c16][q4 * 4];
    const short8 m1 = *(const short8*)&x_lds[nt_mv * 16 + c16][16 + q4 * 4];

#pragma unroll
    for (int ct = 0; ct < 4; ++ct) {
        f32x4 d = {0.f, 0.f, 0.f, 0.f};
        d = __builtin_amdgcn_mfma_f32_16x16x32_bf16(a0, wh0[ct], d, 0, 0, 0);
        d = __builtin_amdgcn_mfma_f32_16x16x32_bf16(a1, wh1[ct], d, 0, 0, 0);
        uint2 pk;
        pk.x = (unsigned)f2bf(d[0] + bhc[ct]) | ((unsigned)f2bf(d[1] + bhc[ct]) << 16);
        pk.y = (unsigned)f2bf(d[2] + bhc[ct]) | ((unsigned)f2bf(d[3] + bhc[ct]) << 16);
        *(uint2*)&mh_lds[ct * 16 + c16][w * 16 + q4 * 4] = pk;
    }
    f32x4 dv0 = {0.f, 0.f, 0.f, 0.f}, dv1 = {0.f, 0.f, 0.f, 0.f};
    dv0 = __builtin_amdgcn_mfma_f32_16x16x32_bf16(m0, wv0[0], dv0, 0, 0, 0);
    dv0 = __builtin_amdgcn_mfma_f32_16x16x32_bf16(m1, wv1[0], dv0, 0, 0, 0);
    dv1 = __builtin_amdgcn_mfma_f32_16x16x32_bf16(m0, wv0[1], dv1, 0, 0, 0);
    dv1 = __builtin_amdgcn_mfma_f32_16x16x32_bf16(m1, wv1[1], dv1, 0, 0, 0);

    __syncthreads();

    // ---- Phase 2: einsum for i-tile (w&3) of this half, c-pair ct0 ----
    f32x4 acc0 = {0.f, 0.f, 0.f, 0.f}, acc1 = {0.f, 0.f, 0.f, 0.f};
    const int ir = (w & 3) * 16 + c16;               // att_lds local row
#pragma unroll
    for (int ks = 0; ks < 4; ++ks) {
        const short8 a  = *(const short8*)&att_lds[ir][ks * 16 + q4 * 4];
        const short8 b0 = *(const short8*)&mh_lds[ct0 * 16 + c16][ks * 32 + q4 * 8];
        const short8 b1 = *(const short8*)&mh_lds[(ct0 + 1) * 16 + c16][ks * 32 + q4 * 8];
        acc0 = __builtin_amdgcn_mfma_f32_16x16x32_bf16(a, b0, acc0, 0, 0, 0);
        acc1 = __builtin_amdgcn_mfma_f32_16x16x32_bf16(a, b1, acc1, 0, 0, 0);
    }

    // ---- Epilogue ----
    {
        const int cc0 = ct0 * 16 + c16;
        const int cc1 = (ct0 + 1) * 16 + c16;
        float* ob0 = out + (((size_t)b * COUT + cc0) * N + il_base + q4 * 4) * T + t;
        float* ob1 = out + (((size_t)b * COUT + cc1) * N + il_base + q4 * 4) * T + t;
#pragma unroll
        for (int e = 0; e < 4; ++e) {
            ob0[e * T] = acc0[e] + as4[e] * (dv0[e] + bvc[0]);
            ob1[e * T] = acc1[e] + as4[e] * (dv1[e] + bvc[1]);
        }
    }
}

// ---------------------------------------------------------------------------
extern "C" void kernel_launch(void* const* d_in, const int* in_sizes, int n_in,
                              void* d_out, int out_size, void* d_ws, size_t ws_size,
                              hipStream_t stream)
{
    const float* x   = (const float*)d_in[0];
    const float* att = (const float*)d_in[1];
    const float* W1  = (const float*)d_in[2];
    const float* b1  = (const float*)d_in[3];
    const float* W2  = (const float*)d_in[4];
    const float* b2  = (const float*)d_in[5];
    float* out = (float*)d_out;

    char* ws = (char*)d_ws;
    unsigned*       xT32   = (unsigned*)ws;                        //   786,432 B
    unsigned*       attT32 = (unsigned*)(ws + 786432);             // 1,572,864 B
    float*          asum_g = (float*)(ws + 2359296);               //    24,576 B
    unsigned short* WfvT   = (unsigned short*)(ws + 2383872);      //     8,192 B
    unsigned short* WfhT   = (unsigned short*)(ws + 2392064);      //     8,192 B
    float*          bvb2   = (float*)(ws + 2400256);               //       256 B
    float*          bh     = (float*)(ws + 2400512);               //       256 B

    k_prep<<<PREP_BLOCKS, 256, 0, stream>>>(x, att, W1, b1, W2, b2,
                                            xT32, attT32, asum_g,
                                            WfvT, WfhT, bvb2, bh);
    k_main<<<MAIN_BLOCKS, 512, 0, stream>>>(xT32, attT32,
                                            WfvT, WfhT, bvb2, bh, asum_g, out);
}